// Round 1
// baseline (428.392 us; speedup 1.0000x reference)
//
#include <hip/hip_runtime.h>

// Depthwise 1D cross-correlation, 13 taps (2K-1, K=7), zero-padded, kernel
// shared across all (b,c) rows. x: (32,512,4096) fp32 -> out same shape.
//
// out[row, l] = sum_{t=0}^{12} coef[t] * x[row, l + t - 6]
//   coef[t] = w[6-t] for t<=6 (reversed "previous" taps), w[t] for t>6.
//
// Memory-bound: 537 MB total traffic -> ~85 us floor at 6.3 TB/s.
// One block per row; row staged in LDS with zero halos; float4 global I/O;
// float4 LDS reads; taps via scalar loads (uniform address).

#define ROW_L 4096
#define KHALF 7
#define TAPS 13
#define HALO 6

__global__ __launch_bounds__(256) void conv13_rows_kernel(
    const float* __restrict__ x,
    const float* __restrict__ w,
    float* __restrict__ out)
{
    __shared__ __align__(16) float s[ROW_L + 2 * HALO + 4];  // s[i] = x[row, i-HALO]

    const int row = blockIdx.x;
    const int tid = threadIdx.x;
    const float* xr = x + (size_t)row * ROW_L;
    float* outr = out + (size_t)row * ROW_L;

    // Taps -> registers (uniform addresses -> s_load, broadcast)
    float c[TAPS];
#pragma unroll
    for (int t = 0; t < TAPS; ++t)
        c[t] = (t <= HALO) ? w[HALO - t] : w[t];

    // Zero halos
    if (tid < HALO) {
        s[tid] = 0.0f;
        s[ROW_L + HALO + tid] = 0.0f;
    }

    // Stage row: 4096 floats = 1024 float4; 256 threads x 4 iters, coalesced.
#pragma unroll
    for (int i = 0; i < 4; ++i) {
        const int j4 = tid + i * 256;          // float4 index 0..1023
        float4 v = ((const float4*)xr)[j4];
        const int base = HALO + j4 * 4;        // scalar LDS writes (base%4 != 0)
        s[base + 0] = v.x;
        s[base + 1] = v.y;
        s[base + 2] = v.z;
        s[base + 3] = v.w;
    }
    __syncthreads();

    // Compute: each thread does 4 groups of 4 outputs (float4 stores).
#pragma unroll
    for (int i = 0; i < 4; ++i) {
        const int j4 = tid + i * 256;
        const int j = j4 * 4;                  // output index, j%4==0 -> s[j] 16B-aligned

        // Need s[j .. j+15]: 4 aligned float4 LDS reads (ds_read_b128).
        const float4 a0 = *(const float4*)&s[j + 0];
        const float4 a1 = *(const float4*)&s[j + 4];
        const float4 a2 = *(const float4*)&s[j + 8];
        const float4 a3 = *(const float4*)&s[j + 12];
        const float r[16] = {a0.x, a0.y, a0.z, a0.w,
                             a1.x, a1.y, a1.z, a1.w,
                             a2.x, a2.y, a2.z, a2.w,
                             a3.x, a3.y, a3.z, a3.w};

        float acc0 = 0.f, acc1 = 0.f, acc2 = 0.f, acc3 = 0.f;
#pragma unroll
        for (int t = 0; t < TAPS; ++t) {
            acc0 = fmaf(c[t], r[t + 0], acc0);
            acc1 = fmaf(c[t], r[t + 1], acc1);
            acc2 = fmaf(c[t], r[t + 2], acc2);
            acc3 = fmaf(c[t], r[t + 3], acc3);
        }

        float4 o;
        o.x = acc0; o.y = acc1; o.z = acc2; o.w = acc3;
        ((float4*)outr)[j4] = o;
    }
}

extern "C" void kernel_launch(void* const* d_in, const int* in_sizes, int n_in,
                              void* d_out, int out_size, void* d_ws, size_t ws_size,
                              hipStream_t stream) {
    const float* x = (const float*)d_in[0];       // (32,512,4096) fp32
    const float* w = (const float*)d_in[1];       // (13,) fp32
    float* out = (float*)d_out;

    const int rows = in_sizes[0] / ROW_L;         // 32*512 = 16384
    conv13_rows_kernel<<<rows, 256, 0, stream>>>(x, w, out);
}